// Round 1
// baseline (236.134 us; speedup 1.0000x reference)
//
#include <hip/hip_runtime.h>
#include <hip/hip_bf16.h>
#include <stdint.h>

#define B_TOK 8192
#define DMODEL 512

typedef __attribute__((ext_vector_type(4))) float f32x4;
typedef __attribute__((ext_vector_type(8))) short bf16x8;
typedef __attribute__((ext_vector_type(4))) short bf16x4;

__device__ __forceinline__ float bf2f(short s) {
    union { uint32_t u; float f; } v;
    v.u = ((uint32_t)(uint16_t)s) << 16;
    return v.f;
}
__device__ __forceinline__ short f2bf(float f) {
    union { float f; uint32_t u; } v; v.f = f;
    uint32_t r = (v.u + 0x7fffu + ((v.u >> 16) & 1u)) >> 16;
    return (short)r;
}
__device__ __forceinline__ float sigm(float x) {
    return __builtin_amdgcn_rcpf(1.0f + __expf(-x));
}

// =====================================================================
// Kernel 1: fused pair-scoring attention.  One workgroup (4 waves) = 2
// tokens = 16 token-heads.  Inputs staged once to bf16 LDS (swizzled).
// Waves split the 35 (u,g)/(m,g) pairs.  Writes mix (fp32) into d_out.
// =====================================================================
__global__ __launch_bounds__(256, 2) void fused_att(
    const float* __restrict__ user, const float* __restrict__ mood,
    const float* __restrict__ genre,
    const float* __restrict__ lw1,  const float* __restrict__ lb1,
    const float* __restrict__ lw2,  const float* __restrict__ lb2,
    const float* __restrict__ sw1,  const float* __restrict__ sb1,
    const float* __restrict__ sw2,  const float* __restrict__ sb2,
    const float* __restrict__ zlw1, const float* __restrict__ zlb1,
    const float* __restrict__ zlw2, const float* __restrict__ zlb2,
    const float* __restrict__ zsw1, const float* __restrict__ zsb1,
    const float* __restrict__ zsw2, const float* __restrict__ zsb2,
    float* __restrict__ mixout)
{
    // 12 arrays x 16 token-heads x 64 k, bf16, 128B rows, XOR-swizzled
    __shared__ __attribute__((aligned(16))) unsigned char in_lds[12 * 16 * 128];
    // per-wave att partials, rows padded to 68 floats (bank spread)
    __shared__ __attribute__((aligned(16))) float att_lds[4][16][68];
    __shared__ float r_lds[2][16];

    const int tid  = threadIdx.x;
    const int lane = tid & 63;
    const int wv   = tid >> 6;
    const int tl   = lane & 15;   // MFMA row (token-head within block)
    const int g16  = lane >> 4;   // k-group
    const int wg   = blockIdx.x;  // token block: tokens [2*wg, 2*wg+2)

    // ---------------- stage inputs fp32 -> bf16 LDS ----------------
    {
        const int t = tid >> 4;          // 0..15 token-head
        const int k = (tid & 15) << 2;   // 0..60
        const int dst_off = t * 128 + ((k * 2) ^ ((t & 7) << 4));
        const size_t src_off = (size_t)wg * 1024 + (size_t)tid * 4;
        #pragma unroll
        for (int a = 0; a < 12; ++a) {
            const float* src; float scl;
            if (a < 4)      { src = user  + (size_t)a       * (B_TOK * DMODEL); scl = 0.125f; }
            else if (a < 9) { src = genre + (size_t)(a - 4) * (B_TOK * DMODEL); scl = 1.0f;  }
            else            { src = mood  + (size_t)(a - 9) * (B_TOK * DMODEL); scl = 0.125f; }
            f32x4 v = *(const f32x4*)(src + src_off);
            bf16x4 b;
            b[0] = f2bf(v[0] * scl); b[1] = f2bf(v[1] * scl);
            b[2] = f2bf(v[2] * scl); b[3] = f2bf(v[3] * scl);
            *(bf16x4*)(in_lds + a * 2048 + dst_off) = b;
        }
    }
    __syncthreads();

    // ---------------- per-wave W1^T B-frags (bf16, registers) -------
    const float *w1p, *b1p, *w2p, *b2p;
    if (wv < 2) { w1p = lw1; b1p = lb1; w2p = lw2; b2p = lb2; }
    else        { w1p = sw1; b1p = sb1; w2p = sw2; b2p = sb2; }

    bf16x8 bw[4][2];
    float  b1v[4], w2v[4];
    #pragma unroll
    for (int nt = 0; nt < 4; ++nt) {
        const int j = nt * 16 + tl;   // output column of the matvec
        #pragma unroll
        for (int s = 0; s < 2; ++s) {
            const float* wr = w1p + j * 64 + s * 32 + g16 * 8;
            f32x4 a0 = *(const f32x4*)wr;
            f32x4 a1 = *(const f32x4*)(wr + 4);
            bf16x8 f;
            f[0]=f2bf(a0[0]); f[1]=f2bf(a0[1]); f[2]=f2bf(a0[2]); f[3]=f2bf(a0[3]);
            f[4]=f2bf(a1[0]); f[5]=f2bf(a1[1]); f[6]=f2bf(a1[2]); f[7]=f2bf(a1[3]);
            bw[nt][s] = f;
        }
        b1v[nt] = b1p[j];
        w2v[nt] = w2p[j];
    }
    const float b2s = b2p[0];

    // ---------------- pair loop ----------------
    // wave0: L pairs 0..9, wave1: L 10..19, wave2: S 0..7, wave3: S 8..14
    int pstart, pcount, sbase;
    if      (wv == 0) { pstart = 0;  pcount = 10; sbase = 0; }
    else if (wv == 1) { pstart = 10; pcount = 10; sbase = 0; }
    else if (wv == 2) { pstart = 0;  pcount = 8;  sbase = 9; }
    else              { pstart = 8;  pcount = 7;  sbase = 9; }

    float att[16];
    #pragma unroll
    for (int i = 0; i < 16; ++i) att[i] = 0.0f;

    const unsigned char* lbase = in_lds;
    const int rowb = tl * 128;
    const int swz  = (tl & 7) << 4;
    const int ko2  = g16 * 16;    // byte offset of this lane's k-slice

    for (int pi = pstart; pi < pstart + pcount; ++pi) {
        const int aA = sbase + pi / 5;      // user (0..3) or mood (9..11)
        const int aB = 4 + pi % 5;          // genre (4..8)
        bf16x8 au0 = *(const bf16x8*)(lbase + aA * 2048 + rowb + (ko2 ^ swz));
        bf16x8 au1 = *(const bf16x8*)(lbase + aA * 2048 + rowb + ((ko2 + 64) ^ swz));
        bf16x8 ag0 = *(const bf16x8*)(lbase + aB * 2048 + rowb + (ko2 ^ swz));
        bf16x8 ag1 = *(const bf16x8*)(lbase + aB * 2048 + rowb + ((ko2 + 64) ^ swz));

        float xf[16];
        bf16x8 xa0, xa1;
        #pragma unroll
        for (int i = 0; i < 8; ++i) {
            xf[i]     = bf2f(au0[i]) * bf2f(ag0[i]);
            xf[i + 8] = bf2f(au1[i]) * bf2f(ag1[i]);
            xa0[i] = f2bf(xf[i]);
            xa1[i] = f2bf(xf[i + 8]);
        }

        f32x4 acc[4];
        #pragma unroll
        for (int nt = 0; nt < 4; ++nt) {
            f32x4 z = {0.f, 0.f, 0.f, 0.f};
            z = __builtin_amdgcn_mfma_f32_16x16x32_bf16(xa0, bw[nt][0], z, 0, 0, 0);
            z = __builtin_amdgcn_mfma_f32_16x16x32_bf16(xa1, bw[nt][1], z, 0, 0, 0);
            acc[nt] = z;
        }

        // score = sum_j sigmoid(h_j) * w2[j] + b2 ; D-layout: row=(l>>4)*4+r, col=l&15
        float p0 = 0.f, p1 = 0.f, p2 = 0.f, p3 = 0.f;
        #pragma unroll
        for (int nt = 0; nt < 4; ++nt) {
            p0 += w2v[nt] * sigm(acc[nt][0] + b1v[nt]);
            p1 += w2v[nt] * sigm(acc[nt][1] + b1v[nt]);
            p2 += w2v[nt] * sigm(acc[nt][2] + b1v[nt]);
            p3 += w2v[nt] * sigm(acc[nt][3] + b1v[nt]);
        }
        #pragma unroll
        for (int m = 1; m < 16; m <<= 1) {
            p0 += __shfl_xor(p0, m);
            p1 += __shfl_xor(p1, m);
            p2 += __shfl_xor(p2, m);
            p3 += __shfl_xor(p3, m);
        }
        p0 += b2s; p1 += b2s; p2 += b2s; p3 += b2s;

        // broadcast score[t = l&15] to every lane (A-frag row layout)
        const int srcl = (tl >> 2) << 4;
        float s0 = __shfl(p0, srcl);
        float s1 = __shfl(p1, srcl);
        float s2 = __shfl(p2, srcl);
        float s3 = __shfl(p3, srcl);
        const int rr = tl & 3;
        float sc = (rr == 0) ? s0 : (rr == 1) ? s1 : (rr == 2) ? s2 : s3;

        #pragma unroll
        for (int i = 0; i < 16; ++i) att[i] += sc * xf[i];
    }

    // ---------------- write att partials ----------------
    {
        float* ap = &att_lds[wv][tl][0] + g16 * 8;
        f32x4 v0 = {att[0],  att[1],  att[2],  att[3]};
        f32x4 v1 = {att[4],  att[5],  att[6],  att[7]};
        f32x4 v2 = {att[8],  att[9],  att[10], att[11]};
        f32x4 v3 = {att[12], att[13], att[14], att[15]};
        *(f32x4*)(ap)      = v0;
        *(f32x4*)(ap + 4)  = v1;
        *(f32x4*)(ap + 32) = v2;
        *(f32x4*)(ap + 36) = v3;
    }
    __syncthreads();

    // ---------------- phase D: gate scores rl / rs ----------------
    if (wv < 2) {
        const float* w1z = (wv == 0) ? zlw1 : zsw1;
        const float* b1z = (wv == 0) ? zlb1 : zsb1;
        const float* w2z = (wv == 0) ? zlw2 : zsw2;
        const float* b2z = (wv == 0) ? zlb2 : zsb2;

        bf16x8 zw[4][2];
        float zb1v[4], zw2v[4];
        #pragma unroll
        for (int nt = 0; nt < 4; ++nt) {
            const int j = nt * 16 + tl;
            #pragma unroll
            for (int s = 0; s < 2; ++s) {
                const float* wr = w1z + j * 64 + s * 32 + g16 * 8;
                f32x4 a0 = *(const f32x4*)wr;
                f32x4 a1 = *(const f32x4*)(wr + 4);
                bf16x8 f;
                f[0]=f2bf(a0[0]); f[1]=f2bf(a0[1]); f[2]=f2bf(a0[2]); f[3]=f2bf(a0[3]);
                f[4]=f2bf(a1[0]); f[5]=f2bf(a1[1]); f[6]=f2bf(a1[2]); f[7]=f2bf(a1[3]);
                zw[nt][s] = f;
            }
            zb1v[nt] = b1z[j];
            zw2v[nt] = w2z[j];
        }
        const float b2zs = b2z[0];

        const float* A0 = &att_lds[wv * 2 + 0][tl][0] + g16 * 8;
        const float* A1 = &att_lds[wv * 2 + 1][tl][0] + g16 * 8;
        f32x4 u0 = *(const f32x4*)A0        + *(const f32x4*)A1;
        f32x4 u1 = *(const f32x4*)(A0 + 4)  + *(const f32x4*)(A1 + 4);
        f32x4 u2 = *(const f32x4*)(A0 + 32) + *(const f32x4*)(A1 + 32);
        f32x4 u3 = *(const f32x4*)(A0 + 36) + *(const f32x4*)(A1 + 36);
        bf16x8 za0, za1;
        za0[0]=f2bf(u0[0]); za0[1]=f2bf(u0[1]); za0[2]=f2bf(u0[2]); za0[3]=f2bf(u0[3]);
        za0[4]=f2bf(u1[0]); za0[5]=f2bf(u1[1]); za0[6]=f2bf(u1[2]); za0[7]=f2bf(u1[3]);
        za1[0]=f2bf(u2[0]); za1[1]=f2bf(u2[1]); za1[2]=f2bf(u2[2]); za1[3]=f2bf(u2[3]);
        za1[4]=f2bf(u3[0]); za1[5]=f2bf(u3[1]); za1[6]=f2bf(u3[2]); za1[7]=f2bf(u3[3]);

        f32x4 acc[4];
        #pragma unroll
        for (int nt = 0; nt < 4; ++nt) {
            f32x4 z = {0.f, 0.f, 0.f, 0.f};
            z = __builtin_amdgcn_mfma_f32_16x16x32_bf16(za0, zw[nt][0], z, 0, 0, 0);
            z = __builtin_amdgcn_mfma_f32_16x16x32_bf16(za1, zw[nt][1], z, 0, 0, 0);
            acc[nt] = z;
        }
        float p0 = 0.f, p1 = 0.f, p2 = 0.f, p3 = 0.f;
        #pragma unroll
        for (int nt = 0; nt < 4; ++nt) {
            p0 += zw2v[nt] * sigm(acc[nt][0] + zb1v[nt]);
            p1 += zw2v[nt] * sigm(acc[nt][1] + zb1v[nt]);
            p2 += zw2v[nt] * sigm(acc[nt][2] + zb1v[nt]);
            p3 += zw2v[nt] * sigm(acc[nt][3] + zb1v[nt]);
        }
        #pragma unroll
        for (int m = 1; m < 16; m <<= 1) {
            p0 += __shfl_xor(p0, m);
            p1 += __shfl_xor(p1, m);
            p2 += __shfl_xor(p2, m);
            p3 += __shfl_xor(p3, m);
        }
        if (tl == 0) {
            r_lds[wv][g16 * 4 + 0] = p0 + b2zs;
            r_lds[wv][g16 * 4 + 1] = p1 + b2zs;
            r_lds[wv][g16 * 4 + 2] = p2 + b2zs;
            r_lds[wv][g16 * 4 + 3] = p3 + b2zs;
        }
    }
    __syncthreads();

    // ---------------- mix + store (fp32 into d_out) ----------------
    {
        const int t = tid >> 4;
        const int k = (tid & 15) << 2;
        f32x4 L = *(const f32x4*)&att_lds[0][t][k] + *(const f32x4*)&att_lds[1][t][k];
        f32x4 S = *(const f32x4*)&att_lds[2][t][k] + *(const f32x4*)&att_lds[3][t][k];
        float r0 = sigm(r_lds[0][t] - r_lds[1][t]);   // softmax2 -> sigmoid(rl-rs)
        f32x4 mx = S + (L - S) * r0;
        *(f32x4*)(mixout + (size_t)wg * 1024 + (size_t)tid * 4) = mx;
    }
}

// =====================================================================
// Kernel 0: lin_w fp32 -> bf16 into workspace (when ws available)
// =====================================================================
__global__ __launch_bounds__(256) void conv_w(const float* __restrict__ w,
                                              short* __restrict__ o)
{
    const size_t i = ((size_t)blockIdx.x * 256 + threadIdx.x) * 4;
    f32x4 v = *(const f32x4*)(w + i);
    bf16x4 b;
    b[0] = f2bf(v[0]); b[1] = f2bf(v[1]); b[2] = f2bf(v[2]); b[3] = f2bf(v[3]);
    *(bf16x4*)(o + i) = b;
}

// =====================================================================
// Kernel 2: out = mix @ lin_w^T + lin_b, IN PLACE on d_out.
// Block owns rows [64*bx, 64*bx+64), full N=512: every read of those
// rows precedes every write (per-wave self-contained 16-row slices).
// =====================================================================
template <bool WSB>
__global__ __launch_bounds__(256, 2) void final_gemm(
    const float* __restrict__ linw, const float* __restrict__ linb,
    const short* __restrict__ wsb, float* io)
{
    const int tid  = threadIdx.x;
    const int lane = tid & 63;
    const int wv   = tid >> 6;
    const int tl   = lane & 15;
    const int g16  = lane >> 4;
    const int row0 = blockIdx.x * 64 + wv * 16;

    f32x4 acc[32];
    #pragma unroll
    for (int nt = 0; nt < 32; ++nt) {
        f32x4 z = {0.f, 0.f, 0.f, 0.f};
        acc[nt] = z;
    }

    for (int ks = 0; ks < 16; ++ks) {
        const int k0 = ks * 32 + g16 * 8;
        const float* ar = io + (size_t)(row0 + tl) * 512 + k0;
        f32x4 a0 = *(const f32x4*)ar;
        f32x4 a1 = *(const f32x4*)(ar + 4);
        bf16x8 af;
        af[0]=f2bf(a0[0]); af[1]=f2bf(a0[1]); af[2]=f2bf(a0[2]); af[3]=f2bf(a0[3]);
        af[4]=f2bf(a1[0]); af[5]=f2bf(a1[1]); af[6]=f2bf(a1[2]); af[7]=f2bf(a1[3]);
        #pragma unroll
        for (int nt = 0; nt < 32; ++nt) {
            const int n = nt * 16 + tl;
            bf16x8 bv;
            if constexpr (WSB) {
                bv = *(const bf16x8*)(wsb + (size_t)n * 512 + k0);
            } else {
                const float* br = linw + (size_t)n * 512 + k0;
                f32x4 b0 = *(const f32x4*)br;
                f32x4 b1 = *(const f32x4*)(br + 4);
                bv[0]=f2bf(b0[0]); bv[1]=f2bf(b0[1]); bv[2]=f2bf(b0[2]); bv[3]=f2bf(b0[3]);
                bv[4]=f2bf(b1[0]); bv[5]=f2bf(b1[1]); bv[6]=f2bf(b1[2]); bv[7]=f2bf(b1[3]);
            }
            acc[nt] = __builtin_amdgcn_mfma_f32_16x16x32_bf16(af, bv, acc[nt], 0, 0, 0);
        }
    }

    #pragma unroll
    for (int nt = 0; nt < 32; ++nt) {
        const int n = nt * 16 + tl;
        const float lb = linb[n];
        #pragma unroll
        for (int r = 0; r < 4; ++r) {
            io[(size_t)(row0 + g16 * 4 + r) * 512 + n] = acc[nt][r] + lb;
        }
    }
}

// =====================================================================
extern "C" void kernel_launch(void* const* d_in, const int* in_sizes, int n_in,
                              void* d_out, int out_size, void* d_ws, size_t ws_size,
                              hipStream_t stream)
{
    const float* user = (const float*)d_in[0];
    const float* mood = (const float*)d_in[1];
    const float* genre= (const float*)d_in[2];
    const float* lw1  = (const float*)d_in[3];
    const float* lb1  = (const float*)d_in[4];
    const float* lw2  = (const float*)d_in[5];
    const float* lb2  = (const float*)d_in[6];
    const float* sw1  = (const float*)d_in[7];
    const float* sb1  = (const float*)d_in[8];
    const float* sw2  = (const float*)d_in[9];
    const float* sb2  = (const float*)d_in[10];
    const float* zlw1 = (const float*)d_in[11];
    const float* zlb1 = (const float*)d_in[12];
    const float* zlw2 = (const float*)d_in[13];
    const float* zlb2 = (const float*)d_in[14];
    const float* zsw1 = (const float*)d_in[15];
    const float* zsb1 = (const float*)d_in[16];
    const float* zsw2 = (const float*)d_in[17];
    const float* zsb2 = (const float*)d_in[18];
    const float* linw = (const float*)d_in[19];
    const float* linb = (const float*)d_in[20];
    float* out = (float*)d_out;

    fused_att<<<8192 / 2, 256, 0, stream>>>(
        user, mood, genre,
        lw1, lb1, lw2, lb2, sw1, sb1, sw2, sb2,
        zlw1, zlb1, zlw2, zlb2, zsw1, zsb1, zsw2, zsb2, out);

    if (ws_size >= (size_t)(512 * 512 * 2)) {
        short* wsb = (short*)d_ws;
        conv_w<<<256, 256, 0, stream>>>(linw, wsb);
        final_gemm<true><<<8192 / 64, 256, 0, stream>>>(linw, linb, wsb, out);
    } else {
        final_gemm<false><<<8192 / 64, 256, 0, stream>>>(linw, linb, nullptr, out);
    }
}

// Round 3
// 90.185 us; speedup vs baseline: 2.6183x; 2.6183x over previous
//
#include <hip/hip_runtime.h>
#include <hip/hip_bf16.h>
#include <stdint.h>

#define B_TOK 8192
#define DMODEL 512

typedef __attribute__((ext_vector_type(4))) float f32x4;
typedef __attribute__((ext_vector_type(8))) short bf16x8;
typedef __attribute__((ext_vector_type(4))) short bf16x4;
typedef __attribute__((ext_vector_type(2))) _Float16 f16x2;
typedef __attribute__((ext_vector_type(4))) _Float16 f16x4;
typedef __attribute__((ext_vector_type(8))) _Float16 f16x8;

__device__ __forceinline__ short f2bf(float f) {
    union { float f; uint32_t u; } v; v.f = f;
    uint32_t r = (v.u + 0x7fffu + ((v.u >> 16) & 1u)) >> 16;
    return (short)r;
}

// cvt_pkrtz returns __fp16 ext_vector(2); bit-cast to our _Float16 vec
__device__ __forceinline__ f16x2 pkrtz(float a, float b) {
    auto r = __builtin_amdgcn_cvt_pkrtz(a, b);
    union { decltype(r) i; f16x2 o; } u; u.i = r;
    return u.o;
}

#define NL2E (-1.44269504089f)
#define L2E  (1.44269504089f)

// ---- shared score-head machinery (swapped-operand MFMA pipeline) ----
// stage1: D1[j][t] = sum_k W1'[j][k] x[k][t] + b1'   (W1',b1' pre-scaled by -log2e)
// stage2: score[t] = sum_j w2[j] sigmoid-ish + b2 via 16x16x16 MFMA, every lane
//         ends up holding score[token = lane&15] in all 4 acc elements.
struct ScoreW {
    f16x8 w1f[4][2];
    f32x4 b1f[4];
    f16x4 w2f[4];
    f32x4 b2v;
};

__device__ __forceinline__ void load_scorew(ScoreW& W,
    const float* __restrict__ w1p, const float* __restrict__ b1p,
    const float* __restrict__ w2p, const float* __restrict__ b2p,
    int tl, int g16)
{
    #pragma unroll
    for (int nt = 0; nt < 4; ++nt) {
        #pragma unroll
        for (int kk = 0; kk < 2; ++kk) {
            const float* wr = w1p + (nt * 16 + tl) * 64 + kk * 32 + g16 * 8;
            f32x4 a0 = *(const f32x4*)wr * NL2E;
            f32x4 a1 = *(const f32x4*)(wr + 4) * NL2E;
            f16x2 p0 = pkrtz(a0[0], a0[1]);
            f16x2 p1 = pkrtz(a0[2], a0[3]);
            f16x2 p2 = pkrtz(a1[0], a1[1]);
            f16x2 p3 = pkrtz(a1[2], a1[3]);
            f16x8 f = {p0[0],p0[1],p1[0],p1[1],p2[0],p2[1],p3[0],p3[1]};
            W.w1f[nt][kk] = f;
        }
        W.b1f[nt] = *(const f32x4*)(b1p + nt * 16 + g16 * 4) * NL2E;
        f32x4 w2 = *(const f32x4*)(w2p + nt * 16 + g16 * 4);
        f16x2 q0 = pkrtz(w2[0], w2[1]);
        f16x2 q1 = pkrtz(w2[2], w2[3]);
        f16x4 w2h = {q0[0], q0[1], q1[0], q1[1]};
        W.w2f[nt] = w2h;
    }
    const float b2 = b2p[0];
    f32x4 bb = {b2, b2, b2, b2};
    W.b2v = bb;
}

__device__ __forceinline__ f32x4 score16(const ScoreW& W, f16x8 xa0, f16x8 xa1)
{
    f32x4 acc1[4];
    #pragma unroll
    for (int nt = 0; nt < 4; ++nt)
        acc1[nt] = __builtin_amdgcn_mfma_f32_16x16x32_f16(W.w1f[nt][0], xa0, W.b1f[nt], 0, 0, 0);
    #pragma unroll
    for (int nt = 0; nt < 4; ++nt)
        acc1[nt] = __builtin_amdgcn_mfma_f32_16x16x32_f16(W.w1f[nt][1], xa1, acc1[nt], 0, 0, 0);
    f32x4 acc2 = W.b2v;
    #pragma unroll
    for (int nt = 0; nt < 4; ++nt) {
        f16x2 s01 = pkrtz(
            __builtin_amdgcn_rcpf(1.0f + __builtin_amdgcn_exp2f(acc1[nt][0])),
            __builtin_amdgcn_rcpf(1.0f + __builtin_amdgcn_exp2f(acc1[nt][1])));
        f16x2 s23 = pkrtz(
            __builtin_amdgcn_rcpf(1.0f + __builtin_amdgcn_exp2f(acc1[nt][2])),
            __builtin_amdgcn_rcpf(1.0f + __builtin_amdgcn_exp2f(acc1[nt][3])));
        f16x4 sb = {s01[0], s01[1], s23[0], s23[1]};
        acc2 = __builtin_amdgcn_mfma_f32_16x16x16f16(W.w2f[nt], sb, acc2, 0, 0, 0);
    }
    return acc2;
}

// =====================================================================
// Kernel 1: fused pair-scoring attention. 1 workgroup = 4 waves = 2
// tokens (16 token-heads). f16 LDS inputs, MFMA score pipeline, packed
// f16 att accumulation. WSB: write mix as bf16 into ws; else f32 d_out.
// =====================================================================
template <bool WSB>
__global__ __launch_bounds__(256, 4) void fused_att(
    const float* __restrict__ user, const float* __restrict__ mood,
    const float* __restrict__ genre,
    const float* __restrict__ lw1,  const float* __restrict__ lb1,
    const float* __restrict__ lw2,  const float* __restrict__ lb2,
    const float* __restrict__ sw1,  const float* __restrict__ sb1,
    const float* __restrict__ sw2,  const float* __restrict__ sb2,
    const float* __restrict__ zlw1, const float* __restrict__ zlb1,
    const float* __restrict__ zlw2, const float* __restrict__ zlb2,
    const float* __restrict__ zsw1, const float* __restrict__ zsb1,
    const float* __restrict__ zsw2, const float* __restrict__ zsb2,
    float* __restrict__ fout, short* __restrict__ bout)
{
    // 12 arrays x 16 token-heads x 64 f16 (128B rows, XOR-swizzled)
    __shared__ __attribute__((aligned(16))) unsigned char in_lds[12 * 16 * 128];
    // per-wave att partials, f16, rows padded to 80 halfs (160B, 16B-mult)
    __shared__ __attribute__((aligned(16))) _Float16 att_lds[4][16][80];
    __shared__ float r_lds[2][16];

    const int tid  = threadIdx.x;
    const int lane = tid & 63;
    const int wv   = tid >> 6;
    const int tl   = lane & 15;   // token-head within block
    const int g16  = lane >> 4;   // k-group
    const int wg   = blockIdx.x;  // tokens [2*wg, 2*wg+2)

    // ---------------- stage inputs fp32 -> f16 LDS ----------------
    {
        const int t = tid >> 4;
        const int k4 = (tid & 15) << 2;
        const int dst_off = t * 128 + ((k4 * 2) ^ ((t & 7) << 4));
        const size_t src_off = (size_t)wg * 1024 + (size_t)tid * 4;
        #pragma unroll
        for (int a = 0; a < 12; ++a) {
            const float* src; float scl;
            if (a < 4)      { src = user  + (size_t)a       * (B_TOK * DMODEL); scl = 0.125f; }
            else if (a < 9) { src = genre + (size_t)(a - 4) * (B_TOK * DMODEL); scl = 1.0f;  }
            else            { src = mood  + (size_t)(a - 9) * (B_TOK * DMODEL); scl = 0.125f; }
            f32x4 v = *(const f32x4*)(src + src_off) * scl;
            f16x2 lo = pkrtz(v[0], v[1]);
            f16x2 hi = pkrtz(v[2], v[3]);
            f16x4 b = {lo[0], lo[1], hi[0], hi[1]};
            *(f16x4*)(in_lds + a * 2048 + dst_off) = b;
        }
    }
    __syncthreads();

    // ---------------- per-wave weights ----------------
    ScoreW W;
    if (wv < 2) load_scorew(W, lw1, lb1, lw2, lb2, tl, g16);
    else        load_scorew(W, sw1, sb1, sw2, sb2, tl, g16);

    // wave0: L 0..9, wave1: L 10..19, wave2: S 0..7, wave3: S 8..14
    int pcount, sbase, pstart;
    if      (wv == 0) { pstart = 0;  pcount = 10; sbase = 0; }
    else if (wv == 1) { pstart = 10; pcount = 10; sbase = 0; }
    else if (wv == 2) { pstart = 0;  pcount = 8;  sbase = 9; }
    else              { pstart = 8;  pcount = 7;  sbase = 9; }

    int aA = sbase + pstart / 5;
    int aB = 4 + pstart % 5;

    f16x8 att0 = {0,0,0,0,0,0,0,0};
    f16x8 att1 = {0,0,0,0,0,0,0,0};

    const unsigned char* lbase = in_lds;
    const int rowb = tl * 128;
    const int swz  = (tl & 7) << 4;
    const int ko2  = g16 * 16;

    for (int pi = 0; pi < pcount; ++pi) {
        const unsigned char* ub = lbase + aA * 2048 + rowb;
        const unsigned char* gb = lbase + aB * 2048 + rowb;
        f16x8 au0 = *(const f16x8*)(ub + (ko2 ^ swz));
        f16x8 au1 = *(const f16x8*)(ub + ((ko2 + 64) ^ swz));
        f16x8 ag0 = *(const f16x8*)(gb + (ko2 ^ swz));
        f16x8 ag1 = *(const f16x8*)(gb + ((ko2 + 64) ^ swz));
        f16x8 xa0 = au0 * ag0;
        f16x8 xa1 = au1 * ag1;

        f32x4 sc4 = score16(W, xa0, xa1);
        _Float16 hs = (_Float16)sc4[0];
        f16x8 scv = {hs, hs, hs, hs, hs, hs, hs, hs};
        att0 += scv * xa0;
        att1 += scv * xa1;

        if (++aB == 9) { aB = 4; ++aA; }
    }

    // ---------------- write att partials (f16) ----------------
    *(f16x8*)&att_lds[wv][tl][g16 * 8]      = att0;
    *(f16x8*)&att_lds[wv][tl][32 + g16 * 8] = att1;
    __syncthreads();

    // ---------------- gate scores rl / rs ----------------
    if (wv < 2) {
        ScoreW ZW;
        if (wv == 0) load_scorew(ZW, zlw1, zlb1, zlw2, zlb2, tl, g16);
        else         load_scorew(ZW, zsw1, zsb1, zsw2, zsb2, tl, g16);

        const int b0 = wv * 2, b1i = wv * 2 + 1;  // wave0 sums L (0,1), wave1 sums S (2,3)
        f16x8 za0 = *(const f16x8*)&att_lds[b0][tl][g16 * 8] +
                    *(const f16x8*)&att_lds[b1i][tl][g16 * 8];
        f16x8 za1 = *(const f16x8*)&att_lds[b0][tl][32 + g16 * 8] +
                    *(const f16x8*)&att_lds[b1i][tl][32 + g16 * 8];
        f32x4 rz = score16(ZW, za0, za1);
        if (g16 == 0) r_lds[wv][tl] = rz[0];
    }
    __syncthreads();

    // ---------------- mix + store ----------------
    {
        const int t = tid >> 4;
        const int k4 = (tid & 15) << 2;
        f16x4 l0 = *(const f16x4*)&att_lds[0][t][k4];
        f16x4 l1 = *(const f16x4*)&att_lds[1][t][k4];
        f16x4 s0 = *(const f16x4*)&att_lds[2][t][k4];
        f16x4 s1 = *(const f16x4*)&att_lds[3][t][k4];
        f16x4 Lh = l0 + l1;
        f16x4 Sh = s0 + s1;
        const float rl = r_lds[0][t], rs = r_lds[1][t];
        const float r0 = __builtin_amdgcn_rcpf(1.0f + __builtin_amdgcn_exp2f((rs - rl) * L2E));
        float o[4];
        #pragma unroll
        for (int i = 0; i < 4; ++i) {
            const float Lf = (float)Lh[i], Sf = (float)Sh[i];
            o[i] = Sf + (Lf - Sf) * r0;
        }
        const size_t base = (size_t)wg * 1024 + (size_t)tid * 4;
        if constexpr (WSB) {
            bf16x4 b = {f2bf(o[0]), f2bf(o[1]), f2bf(o[2]), f2bf(o[3])};
            *(bf16x4*)(bout + base) = b;
        } else {
            f32x4 mx = {o[0], o[1], o[2], o[3]};
            *(f32x4*)(fout + base) = mx;
        }
    }
}

// =====================================================================
// Kernel 0: lin_w fp32 -> bf16 into workspace
// =====================================================================
__global__ __launch_bounds__(256) void conv_w(const float* __restrict__ w,
                                              short* __restrict__ o)
{
    const size_t i = ((size_t)blockIdx.x * 256 + threadIdx.x) * 4;
    f32x4 v = *(const f32x4*)(w + i);
    bf16x4 b;
    b[0] = f2bf(v[0]); b[1] = f2bf(v[1]); b[2] = f2bf(v[2]); b[3] = f2bf(v[3]);
    *(bf16x4*)(o + i) = b;
}

// =====================================================================
// Kernel 2 (ws path): C = mix_bf16 @ linw_bf16^T + linb.
// 64x128 tiles, 512 blocks, reg-prefetch + XOR-swizzled LDS.
// =====================================================================
__global__ __launch_bounds__(256, 2) void final_gemm_ws(
    const short* __restrict__ A, const short* __restrict__ Bw,
    const float* __restrict__ bias, float* __restrict__ C)
{
    __shared__ __attribute__((aligned(16))) short lA[64 * 64];
    __shared__ __attribute__((aligned(16))) short lB[128 * 64];

    const int tid  = threadIdx.x;
    const int lane = tid & 63;
    const int wv   = tid >> 6;
    const int tl   = lane & 15;
    const int g16  = lane >> 4;
    const int wr   = wv >> 1;       // row half (32 rows)
    const int wc   = wv & 1;        // col half (64 cols)
    const int bm   = blockIdx.x & 127;
    const int bn   = blockIdx.x >> 7;
    const int m0   = bm * 64, n0 = bn * 128;

    f32x4 acc[2][4];
    #pragma unroll
    for (int mt = 0; mt < 2; ++mt)
        #pragma unroll
        for (int nt = 0; nt < 4; ++nt) { f32x4 z = {0.f,0.f,0.f,0.f}; acc[mt][nt] = z; }

    bf16x8 ra[2], rb[4];
    auto LD = [&](int ks) {
        #pragma unroll
        for (int i = 0; i < 2; ++i) {
            const int c = tid + i * 256;           // 0..511 -> 64 rows x 8 chunks
            ra[i] = *(const bf16x8*)(A + (size_t)(m0 + (c >> 3)) * 512 + ks * 64 + (c & 7) * 8);
        }
        #pragma unroll
        for (int i = 0; i < 4; ++i) {
            const int c = tid + i * 256;           // 0..1023 -> 128 rows x 8 chunks
            rb[i] = *(const bf16x8*)(Bw + (size_t)(n0 + (c >> 3)) * 512 + ks * 64 + (c & 7) * 8);
        }
    };

    LD(0);
    for (int ks = 0; ks < 8; ++ks) {
        __syncthreads();
        #pragma unroll
        for (int i = 0; i < 2; ++i) {
            const int c = tid + i * 256, row = c >> 3;
            *(bf16x8*)(lA + row * 64 + ((c & 7) ^ (row & 7)) * 8) = ra[i];
        }
        #pragma unroll
        for (int i = 0; i < 4; ++i) {
            const int c = tid + i * 256, row = c >> 3;
            *(bf16x8*)(lB + row * 64 + ((c & 7) ^ (row & 7)) * 8) = rb[i];
        }
        __syncthreads();
        if (ks < 7) LD(ks + 1);
        #pragma unroll
        for (int kk = 0; kk < 2; ++kk) {
            bf16x8 af[2], bfr[4];
            #pragma unroll
            for (int mt = 0; mt < 2; ++mt) {
                const int row = wr * 32 + mt * 16 + tl;
                af[mt] = *(const bf16x8*)(lA + row * 64 + ((kk * 4 + g16) ^ (row & 7)) * 8);
            }
            #pragma unroll
            for (int nt = 0; nt < 4; ++nt) {
                const int row = wc * 64 + nt * 16 + tl;
                bfr[nt] = *(const bf16x8*)(lB + row * 64 + ((kk * 4 + g16) ^ (row & 7)) * 8);
            }
            #pragma unroll
            for (int mt = 0; mt < 2; ++mt)
                #pragma unroll
                for (int nt = 0; nt < 4; ++nt)
                    acc[mt][nt] = __builtin_amdgcn_mfma_f32_16x16x32_bf16(af[mt], bfr[nt], acc[mt][nt], 0, 0, 0);
        }
    }

    #pragma unroll
    for (int nt = 0; nt < 4; ++nt) {
        const int n = n0 + wc * 64 + nt * 16 + tl;
        const float bv = bias[n];
        #pragma unroll
        for (int mt = 0; mt < 2; ++mt) {
            #pragma unroll
            for (int r = 0; r < 4; ++r) {
                C[(size_t)(m0 + wr * 32 + mt * 16 + g16 * 4 + r) * 512 + n] = acc[mt][nt][r] + bv;
            }
        }
    }
}

// =====================================================================
// Fallback (no ws): in-place GEMM on d_out (round-0 version)
// =====================================================================
__global__ __launch_bounds__(256, 2) void final_gemm_ip(
    const float* __restrict__ linw, const float* __restrict__ linb, float* io)
{
    const int tid  = threadIdx.x;
    const int lane = tid & 63;
    const int wv   = tid >> 6;
    const int tl   = lane & 15;
    const int g16  = lane >> 4;
    const int row0 = blockIdx.x * 64 + wv * 16;

    f32x4 acc[32];
    #pragma unroll
    for (int nt = 0; nt < 32; ++nt) { f32x4 z = {0.f,0.f,0.f,0.f}; acc[nt] = z; }

    for (int ks = 0; ks < 16; ++ks) {
        const int k0 = ks * 32 + g16 * 8;
        const float* ar = io + (size_t)(row0 + tl) * 512 + k0;
        f32x4 a0 = *(const f32x4*)ar;
        f32x4 a1 = *(const f32x4*)(ar + 4);
        bf16x8 af;
        af[0]=f2bf(a0[0]); af[1]=f2bf(a0[1]); af[2]=f2bf(a0[2]); af[3]=f2bf(a0[3]);
        af[4]=f2bf(a1[0]); af[5]=f2bf(a1[1]); af[6]=f2bf(a1[2]); af[7]=f2bf(a1[3]);
        #pragma unroll
        for (int nt = 0; nt < 32; ++nt) {
            const int n = nt * 16 + tl;
            const float* br = linw + (size_t)n * 512 + k0;
            f32x4 b0 = *(const f32x4*)br;
            f32x4 b1 = *(const f32x4*)(br + 4);
            bf16x8 bv;
            bv[0]=f2bf(b0[0]); bv[1]=f2bf(b0[1]); bv[2]=f2bf(b0[2]); bv[3]=f2bf(b0[3]);
            bv[4]=f2bf(b1[0]); bv[5]=f2bf(b1[1]); bv[6]=f2bf(b1[2]); bv[7]=f2bf(b1[3]);
            acc[nt] = __builtin_amdgcn_mfma_f32_16x16x32_bf16(af, bv, acc[nt], 0, 0, 0);
        }
    }

    #pragma unroll
    for (int nt = 0; nt < 32; ++nt) {
        const int n = nt * 16 + tl;
        const float lb = linb[n];
        #pragma unroll
        for (int r = 0; r < 4; ++r)
            io[(size_t)(row0 + g16 * 4 + r) * 512 + n] = acc[nt][r] + lb;
    }
}

// =====================================================================
extern "C" void kernel_launch(void* const* d_in, const int* in_sizes, int n_in,
                              void* d_out, int out_size, void* d_ws, size_t ws_size,
                              hipStream_t stream)
{
    const float* user = (const float*)d_in[0];
    const float* mood = (const float*)d_in[1];
    const float* genre= (const float*)d_in[2];
    const float* lw1  = (const float*)d_in[3];
    const float* lb1  = (const float*)d_in[4];
    const float* lw2  = (const float*)d_in[5];
    const float* lb2  = (const float*)d_in[6];
    const float* sw1  = (const float*)d_in[7];
    const float* sb1  = (const float*)d_in[8];
    const float* sw2  = (const float*)d_in[9];
    const float* sb2  = (const float*)d_in[10];
    const float* zlw1 = (const float*)d_in[11];
    const float* zlb1 = (const float*)d_in[12];
    const float* zlw2 = (const float*)d_in[13];
    const float* zlb2 = (const float*)d_in[14];
    const float* zsw1 = (const float*)d_in[15];
    const float* zsb1 = (const float*)d_in[16];
    const float* zsw2 = (const float*)d_in[17];
    const float* zsb2 = (const float*)d_in[18];
    const float* linw = (const float*)d_in[19];
    const float* linb = (const float*)d_in[20];
    float* out = (float*)d_out;

    const size_t WNEED = (size_t)512 * 512 * 2 + (size_t)B_TOK * 512 * 2;
    if (ws_size >= WNEED) {
        short* wb   = (short*)d_ws;
        short* mixb = wb + 512 * 512;
        conv_w<<<256, 256, 0, stream>>>(linw, wb);
        fused_att<true><<<B_TOK / 2, 256, 0, stream>>>(
            user, mood, genre,
            lw1, lb1, lw2, lb2, sw1, sb1, sw2, sb2,
            zlw1, zlb1, zlw2, zlb2, zsw1, zsb1, zsw2, zsb2,
            nullptr, mixb);
        final_gemm_ws<<<512, 256, 0, stream>>>(mixb, wb, linb, out);
    } else {
        fused_att<false><<<B_TOK / 2, 256, 0, stream>>>(
            user, mood, genre,
            lw1, lb1, lw2, lb2, sw1, sb1, sw2, sb2,
            zlw1, zlb1, zlw2, zlb2, zsw1, zsb1, zsw2, zsb2,
            out, nullptr);
        final_gemm_ip<<<B_TOK / 64, 256, 0, stream>>>(linw, linb, out);
    }
}